// Round 5
// baseline (495.525 us; speedup 1.0000x reference)
//
#include <hip/hip_runtime.h>

#define EPS 1e-6f
#define NSTEPS 4
#define TPB 128
#define GROUPS 4          // 32-lane solve groups per block
#define TPG 2             // batch tiles solved simultaneously per group
#define TILES (GROUPS * TPG)   // 8 tiles resident in LDS per block
#define PITCH 33          // LDS row pitch (floats): bank-conflict-free transpose
#define TSTRIDE (32 * PITCH)

// ---------------------------------------------------------------------------
// Kernel 1: precompute Thomas coefficients per (step, c, solve-line).
// P[((s*3+c)*32 + i)*32 + lane] = float4(a_i, 1/denom_i, cs_i, 0)
// lane = h (x-dir) or w (y-dir); i = position along the solve direction.
// (Identical to the proven R1/R4 version.)
// ---------------------------------------------------------------------------
__global__ void coeff_kernel(const float* __restrict__ ab,
                             const float* __restrict__ atc,
                             const float* __restrict__ bb,
                             const float* __restrict__ btc,
                             float4* __restrict__ PX,
                             float4* __restrict__ PY)
{
    int tid = blockIdx.x * blockDim.x + threadIdx.x;
    if (tid >= 768) return;                 // 2 dirs * 4 steps * 3 ch * 32 lanes
    int lane = tid & 31;
    int rest = tid >> 5;                    // 0..23
    int c    = rest % 3;
    int s    = (rest / 3) & 3;
    int dir  = rest / 12;                   // 0 = x, 1 = y
    float t  = 0.15f * (float)s;

    float A[32];
    float dt;
    if (dir == 0) {
        int h = lane;
        const float* pa = ab  + (c * 32 + h) * 32;
        const float* pt = atc + (c * 32 + h) * 32;
        #pragma unroll
        for (int w = 0; w < 32; w++)
            A[w] = fmaxf(pa[w] + t * pt[w], EPS);
        dt = 0.075f;                        // DT/2
    } else {
        int w = lane;
        #pragma unroll
        for (int h = 0; h < 32; h++)
            A[h] = fmaxf(bb[(c * 32 + h) * 32 + w] + t * btc[(c * 32 + h) * 32 + w], EPS);
        dt = 0.15f;                         // DT
    }

    // 3-tap mean with replicate padding
    float S[32];
    #pragma unroll
    for (int i = 0; i < 32; i++) {
        float l = A[(i == 0) ? 0 : i - 1];
        float r = A[(i == 31) ? 31 : i + 1];
        S[i] = (l + A[i] + r) / 3.0f;
    }

    float4* dst = (dir == 0 ? PX : PY) + ((s * 3 + c) * 32) * 32 + lane;
    float cp = 0.0f;
    for (int i = 0; i < 32; i++) {
        float co = S[i] * dt;               // coeff = smoothed * dt / DX^2 (DX=1)
        float a  = -co;
        float b  = (i == 0 || i == 31) ? (1.0f + co) : (1.0f + 2.0f * co);
        float cc = -co;
        float denom = (b - a * cp) + EPS;   // matches ref: eps added every step
        float inv = 1.0f / denom;           // precise division here (cheap)
        float cs  = cc / denom;
        if (i == 31) cs = 0.0f;             // ref zeroes c_star[N-1]
        dst[i * 32] = make_float4(a, inv, cs, 0.0f);
        cp = cs;
    }
}

// ---------------------------------------------------------------------------
// Kernel 2: fused 4-step ADI, 2 tiles per 32-lane group (R4 structure).
// R5 changes (arithmetic bitwise identical to R4):
//  - px coefficients held in registers for the WHOLE step (pa/piv/pc, 96
//    regs): x1 and x2 chains become pure-register (no in-chain memory ops),
//    coefficient loads per step drop 96 -> 64 per group. csr[] == pc[].
//  - every phase's LDS inputs are batch-read into val[] BEFORE the serial
//    chain (ds_reads hoist as a block instead of stalling the chain).
//  - y keeps a private ycs[32] for its backward sweep.
// __launch_bounds__(128,2): 256-VGPR budget; ~192 named regs + ~50 spare
// for hoisting py loads. Do NOT tighten (R0/R3 spilled under tight caps).
// ---------------------------------------------------------------------------
__global__ __launch_bounds__(TPB, 2)
void diffuse_kernel(const float* __restrict__ u,
                    const float4* __restrict__ PX,
                    const float4* __restrict__ PY,
                    const float* __restrict__ coupling,
                    float* __restrict__ out)
{
    __shared__ float lds[TILES * TSTRIDE];

    const int tid = threadIdx.x;
    const int g   = tid >> 5;               // group within block (0..3)
    const int r   = tid & 31;               // lane within group
    // consecutive blocks share c: co-resident blocks keep the same 32 KB
    // coefficient slab hot in L1
    const int nper = gridDim.x / 3;         // blocks per channel
    const int c    = blockIdx.x / nper;
    const long grp = blockIdx.x % nper;
    const long bA  = grp * TILES + g * 2;   // batch of tile A
    const long baseA = (bA * 3 + c) << 10;  // 32*32 floats per (b,c) image
    const long baseB = baseA + 3072;        // batch bA+1, same c: +3*1024 floats

    float* TA = lds + (g * 2 + 0) * TSTRIDE;
    float* TB = lds + (g * 2 + 1) * TSTRIDE;

    // ---- stage global -> LDS (coalesced float4 per 32-lane group) ----
    const float4* sA = (const float4*)(u + baseA);
    const float4* sB = (const float4*)(u + baseB);
    #pragma unroll
    for (int j = 0; j < 8; j++) {
        float4 va = sA[j * 32 + r];
        float4 vb = sB[j * 32 + r];
        int f = (j * 32 + r) * 4;           // linear float index in tile
        int row = f >> 5, col = f & 31;
        float* pa_ = TA + row * PITCH + col;
        float* pb_ = TB + row * PITCH + col;
        pa_[0] = va.x; pa_[1] = va.y; pa_[2] = va.z; pa_[3] = va.w;
        pb_[0] = vb.x; pb_[1] = vb.y; pb_[2] = vb.z; pb_[3] = vb.w;
    }
    const float kc = coupling[c * 3 + c];
    __syncthreads();

    float valA[32], valB[32];
    float pa[32], piv[32], pc[32];          // x-coefficients, resident per step
    float ycs[32];                          // y backward coefficients

    #pragma unroll 1
    for (int s = 0; s < NSTEPS; s++) {
        const float4* px = PX + (s * 3 + c) * 1024 + r;
        const float4* py = PY + (s * 3 + c) * 1024 + r;

        // ---- load x-coefficients for the whole step (batched, reg-resident) ----
        #pragma unroll
        for (int i = 0; i < 32; i++) {
            float4 p = px[i * 32];
            pa[i] = p.x; piv[i] = p.y; pc[i] = p.z;
        }

        // ---------- x half-step #1 (thread = row r): pure-reg chains ----------
        {
            if (s == 0) {
                #pragma unroll
                for (int i = 0; i < 32; i++) {
                    valA[i] = TA[r * PITCH + i];
                    valB[i] = TB[r * PITCH + i];
                }
            }
            float dpA = 0.0f, dpB = 0.0f;
            #pragma unroll
            for (int i = 0; i < 32; i++) {
                dpA = (valA[i] - pa[i] * dpA) * piv[i];
                dpB = (valB[i] - pa[i] * dpB) * piv[i];
                valA[i] = dpA;
                valB[i] = dpB;
            }
            float xA = 0.0f, xB = 0.0f;
            #pragma unroll
            for (int i = 31; i >= 0; i--) {
                xA = valA[i] - pc[i] * xA;
                xB = valB[i] - pc[i] * xB;
                TA[r * PITCH + i] = xA;     // expose rows for y transpose
                TB[r * PITCH + i] = xB;
            }
        }
        __syncthreads();

        // ---------- y full step (thread = col r) ----------
        {
            #pragma unroll
            for (int i = 0; i < 32; i++) {  // batch LDS col reads ahead of chain
                valA[i] = TA[i * PITCH + r];
                valB[i] = TB[i * PITCH + r];
            }
            float dpA = 0.0f, dpB = 0.0f;
            #pragma unroll
            for (int i = 0; i < 32; i++) {
                float4 p = py[i * 32];
                dpA = (valA[i] - p.x * dpA) * p.y;
                dpB = (valB[i] - p.x * dpB) * p.y;
                valA[i] = dpA;
                valB[i] = dpB;
                ycs[i]  = p.z;
            }
            float xA = 0.0f, xB = 0.0f;
            #pragma unroll
            for (int i = 31; i >= 0; i--) {
                xA = valA[i] - ycs[i] * xA;
                xB = valB[i] - ycs[i] * xB;
                TA[i * PITCH + r] = xA;     // expose cols for x transpose
                TB[i * PITCH + r] = xB;
            }
        }
        __syncthreads();

        // ---------- x half-step #2 (thread = row r): pure-reg chains ----------
        {
            #pragma unroll
            for (int i = 0; i < 32; i++) {  // batch LDS row reads ahead of chain
                valA[i] = TA[r * PITCH + i];
                valB[i] = TB[r * PITCH + i];
            }
            float dpA = 0.0f, dpB = 0.0f;
            #pragma unroll
            for (int i = 0; i < 32; i++) {
                dpA = (valA[i] - pa[i] * dpA) * piv[i];
                dpB = (valB[i] - pa[i] * dpB) * piv[i];
                valA[i] = dpA;
                valB[i] = dpB;
            }
            float xA = 0.0f, xB = 0.0f;
            #pragma unroll
            for (int i = 31; i >= 0; i--) {
                xA = valA[i] - pc[i] * xA;   // backward uses UNSCALED neighbor
                xB = valB[i] - pc[i] * xB;
                valA[i] = kc * xA;           // channel-diagonal scale
                valB[i] = kc * xB;
            }
        }
        // no barrier needed: x2 and next x1 touch only this thread's rows
    }

    // ---- write back: regs -> LDS rows -> coalesced global float4 ----
    #pragma unroll
    for (int i = 0; i < 32; i++) {
        TA[r * PITCH + i] = valA[i];
        TB[r * PITCH + i] = valB[i];
    }
    __syncthreads();

    float4* dA4 = (float4*)(out + baseA);
    float4* dB4 = (float4*)(out + baseB);
    #pragma unroll
    for (int j = 0; j < 8; j++) {
        int f = (j * 32 + r) * 4;
        int row = f >> 5, col = f & 31;
        float* pa_ = TA + row * PITCH + col;
        float* pb_ = TB + row * PITCH + col;
        dA4[j * 32 + r] = make_float4(pa_[0], pa_[1], pa_[2], pa_[3]);
        dB4[j * 32 + r] = make_float4(pb_[0], pb_[1], pb_[2], pb_[3]);
    }
}

// ---------------------------------------------------------------------------
extern "C" void kernel_launch(void* const* d_in, const int* in_sizes, int n_in,
                              void* d_out, int out_size, void* d_ws, size_t ws_size,
                              hipStream_t stream) {
    const float* u   = (const float*)d_in[0];
    const float* ab  = (const float*)d_in[1];  // alpha_base
    const float* bb  = (const float*)d_in[2];  // beta_base
    const float* atc = (const float*)d_in[3];  // alpha_time_coeff
    const float* btc = (const float*)d_in[4];  // beta_time_coeff
    const float* cpl = (const float*)d_in[5];  // channel_coupling [3][3]
    float* out = (float*)d_out;

    // workspace: PX (192 KB) then PY (192 KB)
    float4* PX = (float4*)d_ws;
    float4* PY = PX + 4 * 3 * 32 * 32;

    coeff_kernel<<<3, 256, 0, stream>>>(ab, atc, bb, btc, PX, PY);

    int B = in_sizes[0] / (3 * 32 * 32);       // 16384
    int nblocks = (B / TILES) * 3;             // 6144 blocks of 8 tiles
    diffuse_kernel<<<nblocks, TPB, 0, stream>>>(u, PX, PY, cpl, out);
}